// Round 2
// baseline (4581.432 us; speedup 1.0000x reference)
//
#include <hip/hip_runtime.h>

// ---- problem constants ----
#define NB    8
#define HIN   384
#define WIN   384
#define HOUT  192
#define WOUT  192
#define HW_IN (HIN * WIN)          // 147456
#define CNT_BN (NB * HOUT * WOUT)  // 294912

// ---- workspace layout (float offsets) ----
#define WS_MEANS 0       // 512:   per-(n,c) spatial means, n*64+c
#define WS_AGGV  512     // 24576: aggregated vert weights [n][c][t][o]
#define WS_AGGH  25088   // 24576: aggregated horz weights [n][c][t][o]
#define WS_SQW   49664   // 36864: sq weights transposed [c][ky][kx][oc]
#define WS_STATS 86528   // 128:   sum_v[32] sumsq_v[32] sum_h[32] sumsq_h[32]
#define WS_BN    86656   // 128:   scale_v[32] shift_v[32] scale_h[32] shift_h[32]

// ---------------- stats zero ----------------
__global__ void k_zero(float* __restrict__ ws) {
    if (threadIdx.x < 128) ws[WS_STATS + threadIdx.x] = 0.f;
}

// ---------------- per-(n,c) spatial mean ----------------
__global__ __launch_bounds__(256) void k_means(const float* __restrict__ x,
                                               float* __restrict__ ws) {
    int bc = blockIdx.x;  // n*64 + c, 512 blocks
    const float4* p = (const float4*)(x + (size_t)bc * HW_IN);
    float s = 0.f;
    for (int i = threadIdx.x; i < HW_IN / 4; i += 256) {
        float4 v = p[i];
        s += (v.x + v.y) + (v.z + v.w);
    }
    __shared__ float red[256];
    red[threadIdx.x] = s;
    __syncthreads();
    for (int off = 128; off > 0; off >>= 1) {
        if ((int)threadIdx.x < off) red[threadIdx.x] += red[threadIdx.x + off];
        __syncthreads();
    }
    if (threadIdx.x == 0) ws[WS_MEANS + bc] = red[0] * (1.0f / HW_IN);
}

// ---------------- attention + expert aggregation ----------------
__global__ void k_agg(const float* __restrict__ aw_v, const float* __restrict__ ab_v,
                      const float* __restrict__ wv,
                      const float* __restrict__ aw_h, const float* __restrict__ ab_h,
                      const float* __restrict__ wh, float* __restrict__ ws) {
    int n = blockIdx.x;  // 8 blocks
    __shared__ float att[8];  // [0..3] vert, [4..7] horz
    if (threadIdx.x < 8) {
        int k = threadIdx.x & 3;
        int hsel = threadIdx.x >> 2;
        const float* m = ws + WS_MEANS + n * 64 + hsel * 32;
        const float* aw = hsel ? aw_h : aw_v;
        const float* ab = hsel ? ab_h : ab_v;
        float z = ab[k];
        for (int c = 0; c < 32; c++) z += m[c] * aw[k * 32 + c];
        att[threadIdx.x] = 1.0f / (1.0f + expf(-z));
    }
    __syncthreads();
    // dst [c][t][o]: i = (c*3+t)*32 + o ; src [k][o][c][t] = (k*32+o)*96 + (c*3+t)
    for (int i = threadIdx.x; i < 3072; i += 256) {
        int o = i & 31;
        int r = i >> 5;  // c*3 + t
        float sv = 0.f, sh = 0.f;
#pragma unroll
        for (int k = 0; k < 4; k++) {
            sv += att[k]     * wv[(k * 32 + o) * 96 + r];
            sh += att[4 + k] * wh[(k * 32 + o) * 96 + r];
        }
        ws[WS_AGGV + n * 3072 + i] = sv;
        ws[WS_AGGH + n * 3072 + i] = sh;
    }
}

// ---------------- sq weight transpose: [oc][c][ky][kx] -> [c][ky][kx][oc] ----------------
__global__ void k_cvtw(const float* __restrict__ sq_w, float* __restrict__ ws) {
    int i = blockIdx.x * 256 + threadIdx.x;  // 36864 total, grid 144
    int oc = i & 63;
    int r = i >> 6;           // c*9 + (ky*3+kx)
    int c = r / 9, q = r % 9;
    ws[WS_SQW + i] = sq_w[(oc * 64 + c) * 9 + q];
}

// ---------------- square 3x3/s2 conv, 16 oc per thread ----------------
__global__ __launch_bounds__(256) void k_sqconv(const float* __restrict__ x,
                                                const float* __restrict__ sq_b,
                                                const float* __restrict__ ws,
                                                float* __restrict__ out) {
    int lane = threadIdx.x & 63;
    int wv = threadIdx.x >> 6;
    int xo = blockIdx.x * 64 + lane;   // grid.x = 3
    int yo = blockIdx.y * 4 + wv;      // grid.y = 48
    int n = blockIdx.z >> 2;           // grid.z = 32
    int oc0 = (blockIdx.z & 3) * 16;
    const float* wp = ws + WS_SQW + oc0;
    float acc[16];
#pragma unroll
    for (int j = 0; j < 16; j++) acc[j] = sq_b[oc0 + j];
    int ix0 = 2 * xo - 1;
    const float* xb = x + (size_t)n * 64 * HW_IN;
    for (int c = 0; c < 64; c++) {
        const float* xc = xb + (size_t)c * HW_IN;
#pragma unroll
        for (int ky = 0; ky < 3; ky++) {
            int iy = 2 * yo - 1 + ky;   // max 383, min -1; wave-uniform check
            if (iy >= 0) {
                const float* row = xc + (size_t)iy * WIN;
                float v0 = (ix0 >= 0) ? row[ix0] : 0.f;
                float v1 = row[ix0 + 1];
                float v2 = row[ix0 + 2];
                const float* wr = wp + (c * 9 + ky * 3) * 64;  // wave-uniform -> s_load
#pragma unroll
                for (int j = 0; j < 16; j++)
                    acc[j] += v0 * wr[j] + v1 * wr[64 + j] + v2 * wr[128 + j];
            }
        }
    }
    size_t ob = (size_t)n * 128 * HOUT * WOUT + (size_t)yo * WOUT + xo;
#pragma unroll
    for (int j = 0; j < 16; j++) {
        int ci = oc0 + j;                          // concat channel 0..63
        int co = ((ci & 15) << 3) | (ci >> 4);     // channel shuffle g=8
        out[ob + (size_t)co * HOUT * WOUT] = acc[j];
    }
}

// ---------------- CondConv (VERT: 3x1 pad(1,0); else 1x3 pad(0,1)), 8 oc/thread ----------------
template <int VERT, int PASS2>
__global__ __launch_bounds__(256) void k_cond(const float* __restrict__ x,
                                              float* __restrict__ ws,
                                              const float* __restrict__ agg,
                                              float* __restrict__ out) {
    int lane = threadIdx.x & 63;
    int wv = threadIdx.x >> 6;
    int xo = blockIdx.x * 64 + lane;   // grid.x = 3
    int yo = blockIdx.y * 4 + wv;      // grid.y = 48
    int n = blockIdx.z >> 2;           // grid.z = 32
    int oc0 = (blockIdx.z & 3) * 8;
    const float* wn = agg + n * 3072 + oc0;
    float acc[8];
#pragma unroll
    for (int j = 0; j < 8; j++) acc[j] = 0.f;
    const float* xb = x + ((size_t)n * 64 + (VERT ? 0 : 32)) * HW_IN;
    if (VERT) {
        int col = 2 * xo;
        for (int c = 0; c < 32; c++) {
            const float* xc = xb + (size_t)c * HW_IN;
#pragma unroll
            for (int t = 0; t < 3; t++) {
                int iy = 2 * yo - 1 + t;
                if (iy >= 0) {
                    float v = xc[(size_t)iy * WIN + col];
                    const float* wr = wn + (c * 3 + t) * 32;
#pragma unroll
                    for (int j = 0; j < 8; j++) acc[j] += v * wr[j];
                }
            }
        }
    } else {
        int ix0 = 2 * xo - 1;
        for (int c = 0; c < 32; c++) {
            const float* row = xb + (size_t)c * HW_IN + (size_t)(2 * yo) * WIN;
            float v0 = (ix0 >= 0) ? row[ix0] : 0.f;
            float v1 = row[ix0 + 1];
            float v2 = row[ix0 + 2];
            const float* wr = wn + c * 96;
#pragma unroll
            for (int j = 0; j < 8; j++)
                acc[j] += v0 * wr[j] + v1 * wr[32 + j] + v2 * wr[64 + j];
        }
    }
    if (!PASS2) {
        float* st = ws + WS_STATS + (VERT ? 0 : 64);
#pragma unroll
        for (int j = 0; j < 8; j++) {
            float s = acc[j], q = acc[j] * acc[j];
#pragma unroll
            for (int off = 32; off > 0; off >>= 1) {
                s += __shfl_xor(s, off, 64);
                q += __shfl_xor(q, off, 64);
            }
            if (lane == 0) {
                atomicAdd(&st[oc0 + j], s);
                atomicAdd(&st[32 + oc0 + j], q);
            }
        }
    } else {
        const float* bn = ws + WS_BN + (VERT ? 0 : 64);
        size_t ob = (size_t)n * 128 * HOUT * WOUT + (size_t)yo * WOUT + xo;
#pragma unroll
        for (int j = 0; j < 8; j++) {
            int oc = oc0 + j;
            float v = acc[j] * bn[oc] + bn[32 + oc];
            int ci = (VERT ? 64 : 96) + oc;
            int co = ((ci & 15) << 3) | (ci >> 4);
            out[ob + (size_t)co * HOUT * WOUT] = v;
        }
    }
}

// ---------------- BN finalize ----------------
__global__ void k_bnfin(const float* __restrict__ gv, const float* __restrict__ bv,
                        const float* __restrict__ gh, const float* __restrict__ bh,
                        float* __restrict__ ws) {
    int t = threadIdx.x;
    if (t >= 64) return;
    int vh = t >> 5;  // 0 = vert, 1 = horz
    int c = t & 31;
    const float* st = ws + WS_STATS + vh * 64;
    float mean = st[c] * (1.0f / CNT_BN);
    float var = st[32 + c] * (1.0f / CNT_BN) - mean * mean;
    float g = vh ? gh[c] : gv[c];
    float b = vh ? bh[c] : bv[c];
    float scale = g * rsqrtf(var + 1e-5f);
    float* bn = ws + WS_BN + vh * 64;
    bn[c] = scale;
    bn[32 + c] = b - mean * scale;
}

extern "C" void kernel_launch(void* const* d_in, const int* in_sizes, int n_in,
                              void* d_out, int out_size, void* d_ws, size_t ws_size,
                              hipStream_t stream) {
    const float* x    = (const float*)d_in[0];
    const float* sq_w = (const float*)d_in[1];
    const float* sq_b = (const float*)d_in[2];
    const float* aw_v = (const float*)d_in[3];
    const float* ab_v = (const float*)d_in[4];
    const float* w_v  = (const float*)d_in[5];
    const float* gv   = (const float*)d_in[6];
    const float* bv   = (const float*)d_in[7];
    const float* aw_h = (const float*)d_in[8];
    const float* ab_h = (const float*)d_in[9];
    const float* w_h  = (const float*)d_in[10];
    const float* gh   = (const float*)d_in[11];
    const float* bh   = (const float*)d_in[12];
    float* out = (float*)d_out;
    float* ws = (float*)d_ws;

    hipLaunchKernelGGL(k_zero, dim3(1), dim3(128), 0, stream, ws);
    hipLaunchKernelGGL(k_means, dim3(512), dim3(256), 0, stream, x, ws);
    hipLaunchKernelGGL(k_agg, dim3(8), dim3(256), 0, stream,
                       aw_v, ab_v, w_v, aw_h, ab_h, w_h, ws);
    hipLaunchKernelGGL(k_cvtw, dim3(144), dim3(256), 0, stream, sq_w, ws);
    hipLaunchKernelGGL(k_sqconv, dim3(3, 48, 32), dim3(256), 0, stream, x, sq_b, ws, out);
    hipLaunchKernelGGL((k_cond<1, 0>), dim3(3, 48, 32), dim3(256), 0, stream,
                       x, ws, ws + WS_AGGV, out);
    hipLaunchKernelGGL((k_cond<0, 0>), dim3(3, 48, 32), dim3(256), 0, stream,
                       x, ws, ws + WS_AGGH, out);
    hipLaunchKernelGGL(k_bnfin, dim3(1), dim3(64), 0, stream, gv, bv, gh, bh, ws);
    hipLaunchKernelGGL((k_cond<1, 1>), dim3(3, 48, 32), dim3(256), 0, stream,
                       x, ws, ws + WS_AGGV, out);
    hipLaunchKernelGGL((k_cond<0, 1>), dim3(3, 48, 32), dim3(256), 0, stream,
                       x, ws, ws + WS_AGGH, out);
}